// Round 12
// baseline (172.854 us; speedup 1.0000x reference)
//
#include <hip/hip_runtime.h>
#include <hip/hip_bf16.h>

#define RSH 7                  // 128 rows per bucket
#define RPB (1 << RSH)
#define CSH 17                 // col bits in packed record (N < 131072)
#define CMASK ((1 << CSH) - 1)
#define CHUNK_E 8192           // edges per chunk block
#define CAP 4096               // max records per bucket (mean ~2048, 45 sigma)
#define AGG_BLOCKS 2048        // 8 blocks/CU -> full wave capacity

__device__ __forceinline__ unsigned short f2bf(float f) {
    unsigned int u = __float_as_uint(f);
    u += 0x7FFFu + ((u >> 16) & 1u);   // round-to-nearest-even
    return (unsigned short)(u >> 16);
}
__device__ __forceinline__ float bf2f(unsigned short h) {
    return __uint_as_float((unsigned int)h << 16);
}

typedef __attribute__((ext_vector_type(8))) short bf16x8;
typedef __attribute__((ext_vector_type(4))) float f32x4;
typedef __attribute__((ext_vector_type(2))) float f32x2;

// ---------- 1. fused: GEMM via MFMA (blocks < gemmBlocks) + chunk_hist ----------
__global__ __launch_bounds__(512) void gemm_hist(
    const float* __restrict__ H, const float* __restrict__ Wg,
    unsigned short* __restrict__ Hpb, int N,
    const int* __restrict__ row, unsigned short* __restrict__ Ht,
    int E, int nchunk, int nb2, int gemmBlocks)
{
    __shared__ unsigned short Ahi[128 * 128];   // 32 KB each
    __shared__ unsigned short Alo[128 * 128];
    __shared__ unsigned short Whi[128 * 128];   // Wt[n][k]
    __shared__ unsigned short Wlo[128 * 128];
    const int tid = threadIdx.x;

    if (blockIdx.x >= gemmBlocks) {
        int* cnt = (int*)Ahi;
        const int c = blockIdx.x - gemmBlocks;
        for (int i = tid; i < nb2; i += 512) cnt[i] = 0;
        __syncthreads();
        const int e0 = c * CHUNK_E;
        const int e1 = min(e0 + CHUNK_E, E);
        for (int e = e0 + tid; e < e1; e += 512)
            atomicAdd(&cnt[row[e] >> RSH], 1);
        __syncthreads();
        for (int i = tid; i < nb2; i += 512)
            Ht[(size_t)i * nchunk + c] = (unsigned short)cnt[i];
        return;
    }

    const int rbase = blockIdx.x * 128;

    #pragma unroll
    for (int i = 0; i < 4; ++i) {
        int task = tid + 512 * i;          // 2048 tasks
        int n  = task & 127;
        int k0 = (task >> 7) * 8;
        unsigned int hi[4], lo[4];
        #pragma unroll
        for (int j = 0; j < 4; ++j) {
            float w0 = Wg[(size_t)(k0 + 2*j)     * 128 + n];
            float w1 = Wg[(size_t)(k0 + 2*j + 1) * 128 + n];
            unsigned short h0 = f2bf(w0), h1 = f2bf(w1);
            unsigned short l0 = f2bf(w0 - bf2f(h0)), l1 = f2bf(w1 - bf2f(h1));
            hi[j] = (unsigned int)h0 | ((unsigned int)h1 << 16);
            lo[j] = (unsigned int)l0 | ((unsigned int)l1 << 16);
        }
        int byte = (k0 * 2) ^ ((n & 7) << 4);
        *(uint4*)((char*)Whi + n * 256 + byte) = make_uint4(hi[0], hi[1], hi[2], hi[3]);
        *(uint4*)((char*)Wlo + n * 256 + byte) = make_uint4(lo[0], lo[1], lo[2], lo[3]);
    }
    #pragma unroll
    for (int i = 0; i < 8; ++i) {
        int flat = tid + 512 * i;          // 4096 float4-tasks
        int rr = flat >> 5;
        int c4  = (flat & 31) * 4;
        float4 h = make_float4(0.f, 0.f, 0.f, 0.f);
        if (rbase + rr < N)
            h = *(const float4*)&H[(size_t)(rbase + rr) * 128 + c4];
        unsigned short h0 = f2bf(h.x), h1 = f2bf(h.y), h2 = f2bf(h.z), h3 = f2bf(h.w);
        uint2 vh, vl;
        vh.x = (unsigned int)h0 | ((unsigned int)h1 << 16);
        vh.y = (unsigned int)h2 | ((unsigned int)h3 << 16);
        vl.x = (unsigned int)f2bf(h.x - bf2f(h0)) | ((unsigned int)f2bf(h.y - bf2f(h1)) << 16);
        vl.y = (unsigned int)f2bf(h.z - bf2f(h2)) | ((unsigned int)f2bf(h.w - bf2f(h3)) << 16);
        int byte = (c4 * 2) ^ ((rr & 7) << 4);
        *(uint2*)((char*)Ahi + rr * 256 + byte) = vh;
        *(uint2*)((char*)Alo + rr * 256 + byte) = vl;
    }
    __syncthreads();

    const int wid = tid >> 6, lane = tid & 63;
    const int wm = wid >> 1, wn = wid & 1;
    const int lr = lane & 15, lg = lane >> 4;
    f32x4 acc[2][4] = {};

    #pragma unroll
    for (int ks = 0; ks < 4; ++ks) {
        const int kb = ks * 64 + lg * 16;
        bf16x8 ahi[2], alo[2];
        #pragma unroll
        for (int mi = 0; mi < 2; ++mi) {
            int rr = wm * 32 + mi * 16 + lr;
            int sw = kb ^ ((rr & 7) << 4);
            ahi[mi] = *(const bf16x8*)((char*)Ahi + rr * 256 + sw);
            alo[mi] = *(const bf16x8*)((char*)Alo + rr * 256 + sw);
        }
        #pragma unroll
        for (int nf = 0; nf < 4; ++nf) {
            int n = wn * 64 + nf * 16 + lr;
            int sw = kb ^ ((n & 7) << 4);
            bf16x8 bhi = *(const bf16x8*)((char*)Whi + n * 256 + sw);
            bf16x8 blo = *(const bf16x8*)((char*)Wlo + n * 256 + sw);
            #pragma unroll
            for (int mi = 0; mi < 2; ++mi) {
                acc[mi][nf] = __builtin_amdgcn_mfma_f32_16x16x32_bf16(ahi[mi], bhi, acc[mi][nf], 0, 0, 0);
                acc[mi][nf] = __builtin_amdgcn_mfma_f32_16x16x32_bf16(ahi[mi], blo, acc[mi][nf], 0, 0, 0);
                acc[mi][nf] = __builtin_amdgcn_mfma_f32_16x16x32_bf16(alo[mi], bhi, acc[mi][nf], 0, 0, 0);
            }
        }
    }

    #pragma unroll
    for (int mi = 0; mi < 2; ++mi) {
        #pragma unroll
        for (int nf = 0; nf < 4; ++nf) {
            int col = wn * 64 + nf * 16 + lr;
            #pragma unroll
            for (int i = 0; i < 4; ++i) {
                int rr = rbase + wm * 32 + mi * 16 + lg * 4 + i;
                if (rr < N)
                    Hpb[(size_t)rr * 128 + col] = f2bf(acc[mi][nf][i]);
            }
        }
    }
}

// ---------- 2b. per-bucket scan over chunks ----------
__global__ __launch_bounds__(256) void bucket_scan(
    const unsigned short* __restrict__ Ht, unsigned short* __restrict__ rel,
    int* __restrict__ totals, int nchunk)
{
    __shared__ int s[256];
    const int b = blockIdx.x, tid = threadIdx.x;
    int v = (tid < nchunk) ? (int)Ht[(size_t)b * nchunk + tid] : 0;
    s[tid] = v;
    __syncthreads();
    for (int d = 1; d < 256; d <<= 1) {
        int t = (tid >= d) ? s[tid - d] : 0;
        __syncthreads();
        s[tid] += t;
        __syncthreads();
    }
    if (tid < nchunk) rel[(size_t)b * nchunk + tid] = (unsigned short)(s[tid] - v);
    if (tid == 255) totals[b] = s[255];
}

// ---------- 2c. scan bucket totals -> bucketptr ----------
__global__ __launch_bounds__(1024) void bucket_ptr_scan(
    const int* __restrict__ totals, int* __restrict__ bucketptr, int nb2)
{
    __shared__ int s[1024];
    const int tid = threadIdx.x;
    int v = (tid < nb2) ? totals[tid] : 0;
    s[tid] = v;
    __syncthreads();
    for (int d = 1; d < 1024; d <<= 1) {
        int t = (tid >= d) ? s[tid - d] : 0;
        __syncthreads();
        s[tid] += t;
        __syncthreads();
    }
    if (tid < nb2) bucketptr[tid] = s[tid] - v;
    if (tid == nb2 - 1) bucketptr[nb2] = s[tid];
}

// ---------- 2d. atomic-free scatter: in-LDS counting sort by bucket ----------
__global__ __launch_bounds__(256) void chunk_scatter(
    const int* __restrict__ row, const int* __restrict__ col,
    const unsigned short* __restrict__ rel, const int* __restrict__ bucketptr,
    int* __restrict__ colsort, int E, int nchunk, int nb2)
{
    __shared__ int loc[1025];
    __shared__ int cur[1024];
    __shared__ int gb[1024];
    __shared__ unsigned short bid[CHUNK_E];
    __shared__ int ord[CHUNK_E];
    __shared__ int part[256];
    const int tid = threadIdx.x;
    const int c = blockIdx.x;
    const int e0 = c * CHUNK_E;
    const int tot = min(CHUNK_E, E - e0);

    for (int i = tid; i < nb2; i += 256) loc[i] = 0;
    __syncthreads();
    for (int j = tid; j < tot; j += 256)
        atomicAdd(&loc[row[e0 + j] >> RSH], 1);
    __syncthreads();

    const int base = tid * 4;
    int v[4]; int s = 0;
    #pragma unroll
    for (int i = 0; i < 4; ++i) {
        int idx = base + i;
        v[i] = (idx < nb2) ? loc[idx] : 0;
        s += v[i];
    }
    part[tid] = s;
    __syncthreads();
    for (int d = 1; d < 256; d <<= 1) {
        int t = (tid >= d) ? part[tid - d] : 0;
        __syncthreads();
        part[tid] += t;
        __syncthreads();
    }
    int run = part[tid] - s;
    #pragma unroll
    for (int i = 0; i < 4; ++i) {
        int idx = base + i;
        if (idx < nb2) { loc[idx] = run; cur[idx] = run; }
        run += v[i];
    }
    if (tid == 255) loc[nb2] = part[255];
    __syncthreads();

    for (int b = tid; b < nb2; b += 256) {
        gb[b] = bucketptr[b] + (int)rel[(size_t)b * nchunk + c];
        int st = loc[b], en = loc[b + 1];
        for (int j = st; j < en; ++j) bid[j] = (unsigned short)b;
    }
    __syncthreads();

    for (int j = tid; j < tot; j += 256) {
        int r = row[e0 + j], cc = col[e0 + j];
        int b = r >> RSH;
        int p = atomicAdd(&cur[b], 1);
        ord[p] = ((r & (RPB - 1)) << CSH) | cc;
    }
    __syncthreads();

    for (int j = tid; j < tot; j += 256) {
        int b = bid[j];
        colsort[gb[b] + (j - loc[b])] = ord[j];
    }
}

// ---------- 2e. per-bucket: derive rowptr + in-place row sort ----------
__global__ __launch_bounds__(256) void bucket_sort(
    const int* __restrict__ bucketptr, int* __restrict__ rowptr,
    int* __restrict__ colsort, int N)
{
    __shared__ int rcnt[RPB];
    __shared__ int rcur[RPB];
    __shared__ int sc[256];
    __shared__ int ord[CAP];
    const int b = blockIdx.x, tid = threadIdx.x;
    const int rbase = b << RSH;
    const int s0 = bucketptr[b];
    const int cnt = bucketptr[b + 1] - s0;

    if (tid < RPB) rcnt[tid] = 0;
    __syncthreads();
    for (int j = tid; j < cnt; j += 256)
        atomicAdd(&rcnt[colsort[s0 + j] >> CSH], 1);
    __syncthreads();

    int v = (tid < RPB) ? rcnt[tid] : 0;
    sc[tid] = v;
    __syncthreads();
    for (int d = 1; d < RPB; d <<= 1) {
        int t = (tid >= d) ? sc[tid - d] : 0;
        __syncthreads();
        sc[tid] += t;
        __syncthreads();
    }
    if (tid < RPB) {
        int ex = sc[tid] - v;
        rcur[tid] = ex;
        int r = rbase + tid;
        if (r < N) rowptr[r] = s0 + ex;
    }
    if (tid == RPB - 1) {
        int rend = min(rbase + RPB, N);
        rowptr[rend] = s0 + cnt;
    }
    __syncthreads();

    for (int j = tid; j < cnt; j += 256) {
        int rec = colsort[s0 + j];
        int p = atomicAdd(&rcur[rec >> CSH], 1);
        ord[p] = rec & CMASK;
    }
    __syncthreads();
    for (int j = tid; j < cnt; j += 256)
        colsort[s0 + j] = ord[j];
}

// ---------- 2f. edge-balanced wave partition: wstart[w] by binary search ----------
__global__ __launch_bounds__(256) void wave_part(
    const int* __restrict__ rowptr, int* __restrict__ wstart,
    int N, long long E, int nw)
{
    int w = blockIdx.x * 256 + threadIdx.x;
    if (w > nw) return;
    if (w == nw) { wstart[nw] = N; return; }
    long long thr = (long long)w * E;
    int lo = 0, hi = N;
    while (lo < hi) {
        int mid = (lo + hi) >> 1;
        if ((long long)rowptr[mid] * nw >= thr) hi = mid; else lo = mid + 1;
    }
    wstart[w] = lo;
}

// ---------- 3. fused score + softmax + aggregate ----------
// Edge-balanced: wave w processes rows [wstart[w], wstart[w+1]), each row
// shared by 4 groups of 16 lanes, mask-predicated unroll-2, f32x2 packed.
__device__ __forceinline__ void unpack8v(uint4 v, f32x2* p) {
    p[0] = (f32x2){__uint_as_float(v.x << 16), __uint_as_float(v.x & 0xFFFF0000u)};
    p[1] = (f32x2){__uint_as_float(v.y << 16), __uint_as_float(v.y & 0xFFFF0000u)};
    p[2] = (f32x2){__uint_as_float(v.z << 16), __uint_as_float(v.z & 0xFFFF0000u)};
    p[3] = (f32x2){__uint_as_float(v.w << 16), __uint_as_float(v.w & 0xFFFF0000u)};
}

__global__ __launch_bounds__(256) void aggregate_kernel(
    const unsigned short* __restrict__ Hpb, const int* __restrict__ rowptr,
    const int* __restrict__ cols, const float* __restrict__ bias,
    const int* __restrict__ wstart, float* __restrict__ out, int N)
{
    const int lane = threadIdx.x & 63;
    const int wv   = threadIdx.x >> 6;
    const int wid  = blockIdx.x * 4 + wv;
    const int d = lane & 15;
    const int g = lane >> 4;

    const int r0 = wstart[wid];
    const int r1 = wstart[wid + 1];

    const float4* bp = (const float4*)&bias[d * 8];
    const float4 b0 = bp[0], b1 = bp[1];

    for (int r = r0; r < r1; ++r) {
        f32x2 hr2[4];
        unpack8v(*(const uint4*)&Hpb[(size_t)r * 128 + d * 8], hr2);

        f32x2 acc2[4] = {};
        float den = 0.f;
        const int e0 = rowptr[r], e1 = rowptr[r + 1];
        const int elast = e1 - 1;

        for (int e = e0 + g; e < e1; e += 8) {
            const bool m1 = (e + 4 < e1);
            const int eb = m1 ? e + 4 : elast;
            int c0 = cols[e];
            int c1 = cols[eb];
            uint4 v0 = *(const uint4*)&Hpb[(size_t)c0 * 128 + d * 8];
            uint4 v1 = *(const uint4*)&Hpb[(size_t)c1 * 128 + d * 8];
            f32x2 hc0[4], hc1[4];
            unpack8v(v0, hc0);
            unpack8v(v1, hc1);

            f32x2 dp0 = hr2[0] * hc0[0];
            f32x2 dp1 = hr2[0] * hc1[0];
            dp0 += hr2[1] * hc0[1];
            dp1 += hr2[1] * hc1[1];
            dp0 += hr2[2] * hc0[2];
            dp1 += hr2[2] * hc1[2];
            dp0 += hr2[3] * hc0[3];
            dp1 += hr2[3] * hc1[3];
            float dot0 = dp0.x + dp0.y;
            float dot1 = dp1.x + dp1.y;

            dot0 += __shfl_xor(dot0, 1);
            dot1 += __shfl_xor(dot1, 1);
            dot0 += __shfl_xor(dot0, 2);
            dot1 += __shfl_xor(dot1, 2);
            dot0 += __shfl_xor(dot0, 4);
            dot1 += __shfl_xor(dot1, 4);
            dot0 += __shfl_xor(dot0, 8);
            dot1 += __shfl_xor(dot1, 8);

            float s0 = fmaxf(dot0, 0.2f * dot0);
            float s1 = fmaxf(dot1, 0.2f * dot1);
            float ex0 = __expf(s0);
            float ex1 = m1 ? __expf(s1) : 0.f;
            den += ex0 + ex1;
            #pragma unroll
            for (int k = 0; k < 4; ++k) {
                acc2[k] += hc0[k] * ex0;
                acc2[k] += hc1[k] * ex1;
            }
        }

        #pragma unroll
        for (int k = 0; k < 4; ++k) {
            acc2[k].x += __shfl_xor(acc2[k].x, 16);
            acc2[k].y += __shfl_xor(acc2[k].y, 16);
            acc2[k].x += __shfl_xor(acc2[k].x, 32);
            acc2[k].y += __shfl_xor(acc2[k].y, 32);
        }
        den += __shfl_xor(den, 16);
        den += __shfl_xor(den, 32);

        if (g == 0) {
            float inv = 1.f / (den + 1e-10f);
            float4 o0, o1;
            o0.x = fmaf(acc2[0].x, inv, b0.x);
            o0.y = fmaf(acc2[0].y, inv, b0.y);
            o0.z = fmaf(acc2[1].x, inv, b0.z);
            o0.w = fmaf(acc2[1].y, inv, b0.w);
            o1.x = fmaf(acc2[2].x, inv, b1.x);
            o1.y = fmaf(acc2[2].y, inv, b1.y);
            o1.z = fmaf(acc2[3].x, inv, b1.z);
            o1.w = fmaf(acc2[3].y, inv, b1.w);
            float4* op = (float4*)&out[(size_t)r * 128 + d * 8];
            op[0] = o0;
            op[1] = o1;
        }
    }
}

extern "C" void kernel_launch(void* const* d_in, const int* in_sizes, int n_in,
                              void* d_out, int out_size, void* d_ws, size_t ws_size,
                              hipStream_t stream)
{
    const float* H    = (const float*)d_in[0];
    const float* W    = (const float*)d_in[1];
    const float* bias = (const float*)d_in[2];
    const int*   row  = (const int*)d_in[3];
    const int*   col  = (const int*)d_in[4];
    const int N = in_sizes[0] / 128;
    const int E = in_sizes[3];

    const int nchunk = (E + CHUNK_E - 1) / CHUNK_E;   // 196
    const int nb2    = (N + RPB - 1) / RPB;           // 782
    const int nw     = AGG_BLOCKS * 4;                // 8192 waves

    auto align = [](size_t x) { return (x + 255) & ~(size_t)255; };

    char* ws = (char*)d_ws;
    size_t off = 0;
    unsigned short* Hpb       = (unsigned short*)(ws + off); off = align(off + (size_t)N * 128 * 2);
    unsigned short* Ht        = (unsigned short*)(ws + off); off = align(off + (size_t)nb2 * nchunk * 2);
    unsigned short* rel       = (unsigned short*)(ws + off); off = align(off + (size_t)nb2 * nchunk * 2);
    int*            totals    = (int*)(ws + off);            off = align(off + (size_t)nb2 * 4);
    int*            bucketptr = (int*)(ws + off);            off = align(off + (size_t)(nb2 + 1) * 4);
    int*            rowptr    = (int*)(ws + off);            off = align(off + (size_t)(N + 1) * 4);
    int*            wstart    = (int*)(ws + off);            off = align(off + (size_t)(nw + 1) * 4);
    int*            colsort   = (int*)(ws + off);

    const int gemmBlocks = (N + 127) / 128;

    gemm_hist<<<gemmBlocks + nchunk, 512, 0, stream>>>(H, W, Hpb, N,
                                                       row, Ht, E, nchunk, nb2,
                                                       gemmBlocks);
    bucket_scan<<<nb2, 256, 0, stream>>>(Ht, rel, totals, nchunk);
    bucket_ptr_scan<<<1, 1024, 0, stream>>>(totals, bucketptr, nb2);
    chunk_scatter<<<nchunk, 256, 0, stream>>>(row, col, rel, bucketptr,
                                              colsort, E, nchunk, nb2);
    bucket_sort<<<nb2, 256, 0, stream>>>(bucketptr, rowptr, colsort, N);
    wave_part<<<(nw + 256) / 256, 256, 0, stream>>>(rowptr, wstart, N,
                                                    (long long)E, nw);
    aggregate_kernel<<<AGG_BLOCKS, 256, 0, stream>>>(Hpb, rowptr, colsort, bias,
                                                     wstart, (float*)d_out, N);
}

// Round 13
// 145.449 us; speedup vs baseline: 1.1884x; 1.1884x over previous
//
#include <hip/hip_runtime.h>
#include <hip/hip_bf16.h>

#define RSH 7                  // 128 rows per bucket
#define RPB (1 << RSH)
#define CSH 17                 // col bits in packed record (N < 131072)
#define CMASK ((1 << CSH) - 1)
#define CHUNK_E 8192           // edges per chunk block
#define CAP 4096               // max records per bucket (mean ~2048, 45 sigma)

__device__ __forceinline__ unsigned short f2bf(float f) {
    unsigned int u = __float_as_uint(f);
    u += 0x7FFFu + ((u >> 16) & 1u);   // round-to-nearest-even
    return (unsigned short)(u >> 16);
}
__device__ __forceinline__ float bf2f(unsigned short h) {
    return __uint_as_float((unsigned int)h << 16);
}

typedef __attribute__((ext_vector_type(8))) short bf16x8;
typedef __attribute__((ext_vector_type(4))) float f32x4;
typedef __attribute__((ext_vector_type(2))) float f32x2;

// ---------- 1. fused: GEMM via MFMA (blocks < gemmBlocks) + chunk_hist ----------
__global__ __launch_bounds__(512) void gemm_hist(
    const float* __restrict__ H, const float* __restrict__ Wg,
    unsigned short* __restrict__ Hpb, int N,
    const int* __restrict__ row, unsigned short* __restrict__ Ht,
    int E, int nchunk, int nb2, int gemmBlocks)
{
    __shared__ unsigned short Ahi[128 * 128];   // 32 KB each
    __shared__ unsigned short Alo[128 * 128];
    __shared__ unsigned short Whi[128 * 128];   // Wt[n][k]
    __shared__ unsigned short Wlo[128 * 128];
    const int tid = threadIdx.x;

    if (blockIdx.x >= gemmBlocks) {
        int* cnt = (int*)Ahi;
        const int c = blockIdx.x - gemmBlocks;
        for (int i = tid; i < nb2; i += 512) cnt[i] = 0;
        __syncthreads();
        const int e0 = c * CHUNK_E;
        const int e1 = min(e0 + CHUNK_E, E);
        for (int e = e0 + tid; e < e1; e += 512)
            atomicAdd(&cnt[row[e] >> RSH], 1);
        __syncthreads();
        for (int i = tid; i < nb2; i += 512)
            Ht[(size_t)i * nchunk + c] = (unsigned short)cnt[i];
        return;
    }

    const int rbase = blockIdx.x * 128;

    #pragma unroll
    for (int i = 0; i < 4; ++i) {
        int task = tid + 512 * i;          // 2048 tasks
        int n  = task & 127;
        int k0 = (task >> 7) * 8;
        unsigned int hi[4], lo[4];
        #pragma unroll
        for (int j = 0; j < 4; ++j) {
            float w0 = Wg[(size_t)(k0 + 2*j)     * 128 + n];
            float w1 = Wg[(size_t)(k0 + 2*j + 1) * 128 + n];
            unsigned short h0 = f2bf(w0), h1 = f2bf(w1);
            unsigned short l0 = f2bf(w0 - bf2f(h0)), l1 = f2bf(w1 - bf2f(h1));
            hi[j] = (unsigned int)h0 | ((unsigned int)h1 << 16);
            lo[j] = (unsigned int)l0 | ((unsigned int)l1 << 16);
        }
        int byte = (k0 * 2) ^ ((n & 7) << 4);
        *(uint4*)((char*)Whi + n * 256 + byte) = make_uint4(hi[0], hi[1], hi[2], hi[3]);
        *(uint4*)((char*)Wlo + n * 256 + byte) = make_uint4(lo[0], lo[1], lo[2], lo[3]);
    }
    #pragma unroll
    for (int i = 0; i < 8; ++i) {
        int flat = tid + 512 * i;          // 4096 float4-tasks
        int rr = flat >> 5;
        int c4  = (flat & 31) * 4;
        float4 h = make_float4(0.f, 0.f, 0.f, 0.f);
        if (rbase + rr < N)
            h = *(const float4*)&H[(size_t)(rbase + rr) * 128 + c4];
        unsigned short h0 = f2bf(h.x), h1 = f2bf(h.y), h2 = f2bf(h.z), h3 = f2bf(h.w);
        uint2 vh, vl;
        vh.x = (unsigned int)h0 | ((unsigned int)h1 << 16);
        vh.y = (unsigned int)h2 | ((unsigned int)h3 << 16);
        vl.x = (unsigned int)f2bf(h.x - bf2f(h0)) | ((unsigned int)f2bf(h.y - bf2f(h1)) << 16);
        vl.y = (unsigned int)f2bf(h.z - bf2f(h2)) | ((unsigned int)f2bf(h.w - bf2f(h3)) << 16);
        int byte = (c4 * 2) ^ ((rr & 7) << 4);
        *(uint2*)((char*)Ahi + rr * 256 + byte) = vh;
        *(uint2*)((char*)Alo + rr * 256 + byte) = vl;
    }
    __syncthreads();

    const int wid = tid >> 6, lane = tid & 63;
    const int wm = wid >> 1, wn = wid & 1;
    const int lr = lane & 15, lg = lane >> 4;
    f32x4 acc[2][4] = {};

    #pragma unroll
    for (int ks = 0; ks < 4; ++ks) {
        const int kb = ks * 64 + lg * 16;
        bf16x8 ahi[2], alo[2];
        #pragma unroll
        for (int mi = 0; mi < 2; ++mi) {
            int rr = wm * 32 + mi * 16 + lr;
            int sw = kb ^ ((rr & 7) << 4);
            ahi[mi] = *(const bf16x8*)((char*)Ahi + rr * 256 + sw);
            alo[mi] = *(const bf16x8*)((char*)Alo + rr * 256 + sw);
        }
        #pragma unroll
        for (int nf = 0; nf < 4; ++nf) {
            int n = wn * 64 + nf * 16 + lr;
            int sw = kb ^ ((n & 7) << 4);
            bf16x8 bhi = *(const bf16x8*)((char*)Whi + n * 256 + sw);
            bf16x8 blo = *(const bf16x8*)((char*)Wlo + n * 256 + sw);
            #pragma unroll
            for (int mi = 0; mi < 2; ++mi) {
                acc[mi][nf] = __builtin_amdgcn_mfma_f32_16x16x32_bf16(ahi[mi], bhi, acc[mi][nf], 0, 0, 0);
                acc[mi][nf] = __builtin_amdgcn_mfma_f32_16x16x32_bf16(ahi[mi], blo, acc[mi][nf], 0, 0, 0);
                acc[mi][nf] = __builtin_amdgcn_mfma_f32_16x16x32_bf16(alo[mi], bhi, acc[mi][nf], 0, 0, 0);
            }
        }
    }

    #pragma unroll
    for (int mi = 0; mi < 2; ++mi) {
        #pragma unroll
        for (int nf = 0; nf < 4; ++nf) {
            int col = wn * 64 + nf * 16 + lr;
            #pragma unroll
            for (int i = 0; i < 4; ++i) {
                int rr = rbase + wm * 32 + mi * 16 + lg * 4 + i;
                if (rr < N)
                    Hpb[(size_t)rr * 128 + col] = f2bf(acc[mi][nf][i]);
            }
        }
    }
}

// ---------- 2b. per-bucket scan over chunks ----------
__global__ __launch_bounds__(256) void bucket_scan(
    const unsigned short* __restrict__ Ht, unsigned short* __restrict__ rel,
    int* __restrict__ totals, int nchunk)
{
    __shared__ int s[256];
    const int b = blockIdx.x, tid = threadIdx.x;
    int v = (tid < nchunk) ? (int)Ht[(size_t)b * nchunk + tid] : 0;
    s[tid] = v;
    __syncthreads();
    for (int d = 1; d < 256; d <<= 1) {
        int t = (tid >= d) ? s[tid - d] : 0;
        __syncthreads();
        s[tid] += t;
        __syncthreads();
    }
    if (tid < nchunk) rel[(size_t)b * nchunk + tid] = (unsigned short)(s[tid] - v);
    if (tid == 255) totals[b] = s[255];
}

// ---------- 2c. scan bucket totals -> bucketptr ----------
__global__ __launch_bounds__(1024) void bucket_ptr_scan(
    const int* __restrict__ totals, int* __restrict__ bucketptr, int nb2)
{
    __shared__ int s[1024];
    const int tid = threadIdx.x;
    int v = (tid < nb2) ? totals[tid] : 0;
    s[tid] = v;
    __syncthreads();
    for (int d = 1; d < 1024; d <<= 1) {
        int t = (tid >= d) ? s[tid - d] : 0;
        __syncthreads();
        s[tid] += t;
        __syncthreads();
    }
    if (tid < nb2) bucketptr[tid] = s[tid] - v;
    if (tid == nb2 - 1) bucketptr[nb2] = s[tid];
}

// ---------- 2d. atomic-free scatter: in-LDS counting sort by bucket ----------
__global__ __launch_bounds__(256) void chunk_scatter(
    const int* __restrict__ row, const int* __restrict__ col,
    const unsigned short* __restrict__ rel, const int* __restrict__ bucketptr,
    int* __restrict__ colsort, int E, int nchunk, int nb2)
{
    __shared__ int loc[1025];
    __shared__ int cur[1024];
    __shared__ int gb[1024];
    __shared__ unsigned short bid[CHUNK_E];
    __shared__ int ord[CHUNK_E];
    __shared__ int part[256];
    const int tid = threadIdx.x;
    const int c = blockIdx.x;
    const int e0 = c * CHUNK_E;
    const int tot = min(CHUNK_E, E - e0);

    for (int i = tid; i < nb2; i += 256) loc[i] = 0;
    __syncthreads();
    for (int j = tid; j < tot; j += 256)
        atomicAdd(&loc[row[e0 + j] >> RSH], 1);
    __syncthreads();

    const int base = tid * 4;
    int v[4]; int s = 0;
    #pragma unroll
    for (int i = 0; i < 4; ++i) {
        int idx = base + i;
        v[i] = (idx < nb2) ? loc[idx] : 0;
        s += v[i];
    }
    part[tid] = s;
    __syncthreads();
    for (int d = 1; d < 256; d <<= 1) {
        int t = (tid >= d) ? part[tid - d] : 0;
        __syncthreads();
        part[tid] += t;
        __syncthreads();
    }
    int run = part[tid] - s;
    #pragma unroll
    for (int i = 0; i < 4; ++i) {
        int idx = base + i;
        if (idx < nb2) { loc[idx] = run; cur[idx] = run; }
        run += v[i];
    }
    if (tid == 255) loc[nb2] = part[255];
    __syncthreads();

    for (int b = tid; b < nb2; b += 256) {
        gb[b] = bucketptr[b] + (int)rel[(size_t)b * nchunk + c];
        int st = loc[b], en = loc[b + 1];
        for (int j = st; j < en; ++j) bid[j] = (unsigned short)b;
    }
    __syncthreads();

    for (int j = tid; j < tot; j += 256) {
        int r = row[e0 + j], cc = col[e0 + j];
        int b = r >> RSH;
        int p = atomicAdd(&cur[b], 1);
        ord[p] = ((r & (RPB - 1)) << CSH) | cc;
    }
    __syncthreads();

    for (int j = tid; j < tot; j += 256) {
        int b = bid[j];
        colsort[gb[b] + (j - loc[b])] = ord[j];
    }
}

// ---------- 2e. per-bucket: derive rowptr + in-place row sort ----------
__global__ __launch_bounds__(256) void bucket_sort(
    const int* __restrict__ bucketptr, int* __restrict__ rowptr,
    int* __restrict__ colsort, int N)
{
    __shared__ int rcnt[RPB];
    __shared__ int rcur[RPB];
    __shared__ int sc[256];
    __shared__ int ord[CAP];
    const int b = blockIdx.x, tid = threadIdx.x;
    const int rbase = b << RSH;
    const int s0 = bucketptr[b];
    const int cnt = bucketptr[b + 1] - s0;

    if (tid < RPB) rcnt[tid] = 0;
    __syncthreads();
    for (int j = tid; j < cnt; j += 256)
        atomicAdd(&rcnt[colsort[s0 + j] >> CSH], 1);
    __syncthreads();

    int v = (tid < RPB) ? rcnt[tid] : 0;
    sc[tid] = v;
    __syncthreads();
    for (int d = 1; d < RPB; d <<= 1) {
        int t = (tid >= d) ? sc[tid - d] : 0;
        __syncthreads();
        sc[tid] += t;
        __syncthreads();
    }
    if (tid < RPB) {
        int ex = sc[tid] - v;
        rcur[tid] = ex;
        int r = rbase + tid;
        if (r < N) rowptr[r] = s0 + ex;
    }
    if (tid == RPB - 1) {
        int rend = min(rbase + RPB, N);
        rowptr[rend] = s0 + cnt;
    }
    __syncthreads();

    for (int j = tid; j < cnt; j += 256) {
        int rec = colsort[s0 + j];
        int p = atomicAdd(&rcur[rec >> CSH], 1);
        ord[p] = rec & CMASK;
    }
    __syncthreads();
    for (int j = tid; j < cnt; j += 256)
        colsort[s0 + j] = ord[j];
}

// ---------- 3. fused score + softmax + aggregate ----------
// 16 rows/block, 4 waves work-steal rows via LDS cursor (dynamic intra-block
// balance, many blocks keep HW dispatcher balancing inter-block).
__device__ __forceinline__ void unpack8v(uint4 v, f32x2* p) {
    p[0] = (f32x2){__uint_as_float(v.x << 16), __uint_as_float(v.x & 0xFFFF0000u)};
    p[1] = (f32x2){__uint_as_float(v.y << 16), __uint_as_float(v.y & 0xFFFF0000u)};
    p[2] = (f32x2){__uint_as_float(v.z << 16), __uint_as_float(v.z & 0xFFFF0000u)};
    p[3] = (f32x2){__uint_as_float(v.w << 16), __uint_as_float(v.w & 0xFFFF0000u)};
}

__global__ __launch_bounds__(256) void aggregate_kernel(
    const unsigned short* __restrict__ Hpb, const int* __restrict__ rowptr,
    const int* __restrict__ cols, const float* __restrict__ bias,
    float* __restrict__ out, int N)
{
    __shared__ int cursor;
    const int lane = threadIdx.x & 63;
    const int d = lane & 15;
    const int g = lane >> 4;
    const int rbase = blockIdx.x * 16;
    if (threadIdx.x == 0) cursor = 0;
    __syncthreads();

    const float4* bp = (const float4*)&bias[d * 8];
    const float4 b0 = bp[0], b1 = bp[1];

    for (;;) {
        int idx = 0;
        if (lane == 0) idx = atomicAdd(&cursor, 1);
        idx = __shfl(idx, 0);
        if (idx >= 16) break;
        const int r = rbase + idx;
        if (r >= N) continue;

        f32x2 hr2[4];
        unpack8v(*(const uint4*)&Hpb[(size_t)r * 128 + d * 8], hr2);

        f32x2 acc2[4] = {};
        float den = 0.f;
        const int e0 = rowptr[r], e1 = rowptr[r + 1];
        const int elast = e1 - 1;

        for (int e = e0 + g; e < e1; e += 8) {
            const bool m1 = (e + 4 < e1);
            const int eb = m1 ? e + 4 : elast;
            int c0 = cols[e];
            int c1 = cols[eb];
            uint4 v0 = *(const uint4*)&Hpb[(size_t)c0 * 128 + d * 8];
            uint4 v1 = *(const uint4*)&Hpb[(size_t)c1 * 128 + d * 8];
            f32x2 hc0[4], hc1[4];
            unpack8v(v0, hc0);
            unpack8v(v1, hc1);

            f32x2 dp0 = hr2[0] * hc0[0];
            f32x2 dp1 = hr2[0] * hc1[0];
            dp0 += hr2[1] * hc0[1];
            dp1 += hr2[1] * hc1[1];
            dp0 += hr2[2] * hc0[2];
            dp1 += hr2[2] * hc1[2];
            dp0 += hr2[3] * hc0[3];
            dp1 += hr2[3] * hc1[3];
            float dot0 = dp0.x + dp0.y;
            float dot1 = dp1.x + dp1.y;

            dot0 += __shfl_xor(dot0, 1);
            dot1 += __shfl_xor(dot1, 1);
            dot0 += __shfl_xor(dot0, 2);
            dot1 += __shfl_xor(dot1, 2);
            dot0 += __shfl_xor(dot0, 4);
            dot1 += __shfl_xor(dot1, 4);
            dot0 += __shfl_xor(dot0, 8);
            dot1 += __shfl_xor(dot1, 8);

            float s0 = fmaxf(dot0, 0.2f * dot0);
            float s1 = fmaxf(dot1, 0.2f * dot1);
            float ex0 = __expf(s0);
            float ex1 = m1 ? __expf(s1) : 0.f;
            den += ex0 + ex1;
            #pragma unroll
            for (int k = 0; k < 4; ++k) {
                acc2[k] += hc0[k] * ex0;
                acc2[k] += hc1[k] * ex1;
            }
        }

        #pragma unroll
        for (int k = 0; k < 4; ++k) {
            acc2[k].x += __shfl_xor(acc2[k].x, 16);
            acc2[k].y += __shfl_xor(acc2[k].y, 16);
            acc2[k].x += __shfl_xor(acc2[k].x, 32);
            acc2[k].y += __shfl_xor(acc2[k].y, 32);
        }
        den += __shfl_xor(den, 16);
        den += __shfl_xor(den, 32);

        if (g == 0) {
            float inv = 1.f / (den + 1e-10f);
            float4 o0, o1;
            o0.x = fmaf(acc2[0].x, inv, b0.x);
            o0.y = fmaf(acc2[0].y, inv, b0.y);
            o0.z = fmaf(acc2[1].x, inv, b0.z);
            o0.w = fmaf(acc2[1].y, inv, b0.w);
            o1.x = fmaf(acc2[2].x, inv, b1.x);
            o1.y = fmaf(acc2[2].y, inv, b1.y);
            o1.z = fmaf(acc2[3].x, inv, b1.z);
            o1.w = fmaf(acc2[3].y, inv, b1.w);
            float4* op = (float4*)&out[(size_t)r * 128 + d * 8];
            op[0] = o0;
            op[1] = o1;
        }
    }
}

extern "C" void kernel_launch(void* const* d_in, const int* in_sizes, int n_in,
                              void* d_out, int out_size, void* d_ws, size_t ws_size,
                              hipStream_t stream)
{
    const float* H    = (const float*)d_in[0];
    const float* W    = (const float*)d_in[1];
    const float* bias = (const float*)d_in[2];
    const int*   row  = (const int*)d_in[3];
    const int*   col  = (const int*)d_in[4];
    const int N = in_sizes[0] / 128;
    const int E = in_sizes[3];

    const int nchunk = (E + CHUNK_E - 1) / CHUNK_E;   // 196
    const int nb2    = (N + RPB - 1) / RPB;           // 782

    auto align = [](size_t x) { return (x + 255) & ~(size_t)255; };

    char* ws = (char*)d_ws;
    size_t off = 0;
    unsigned short* Hpb       = (unsigned short*)(ws + off); off = align(off + (size_t)N * 128 * 2);
    unsigned short* Ht        = (unsigned short*)(ws + off); off = align(off + (size_t)nb2 * nchunk * 2);
    unsigned short* rel       = (unsigned short*)(ws + off); off = align(off + (size_t)nb2 * nchunk * 2);
    int*            totals    = (int*)(ws + off);            off = align(off + (size_t)nb2 * 4);
    int*            bucketptr = (int*)(ws + off);            off = align(off + (size_t)(nb2 + 1) * 4);
    int*            rowptr    = (int*)(ws + off);            off = align(off + (size_t)(N + 1) * 4);
    int*            colsort   = (int*)(ws + off);

    const int gemmBlocks = (N + 127) / 128;

    gemm_hist<<<gemmBlocks + nchunk, 512, 0, stream>>>(H, W, Hpb, N,
                                                       row, Ht, E, nchunk, nb2,
                                                       gemmBlocks);
    bucket_scan<<<nb2, 256, 0, stream>>>(Ht, rel, totals, nchunk);
    bucket_ptr_scan<<<1, 1024, 0, stream>>>(totals, bucketptr, nb2);
    chunk_scatter<<<nchunk, 256, 0, stream>>>(row, col, rel, bucketptr,
                                              colsort, E, nchunk, nb2);
    bucket_sort<<<nb2, 256, 0, stream>>>(bucketptr, rowptr, colsort, N);
    aggregate_kernel<<<(N + 15) / 16, 256, 0, stream>>>(Hpb, rowptr, colsort, bias,
                                                        (float*)d_out, N);
}

// Round 14
// 138.866 us; speedup vs baseline: 1.2448x; 1.0474x over previous
//
#include <hip/hip_runtime.h>
#include <hip/hip_bf16.h>

#define RSH 7                  // 128 rows per bucket
#define RPB (1 << RSH)
#define CSH 17                 // col bits in packed record (N < 131072)
#define CMASK ((1 << CSH) - 1)
#define CHUNK_E 8192           // edges per chunk block
#define CAP 4096               // max records per bucket (mean ~2048, 45 sigma)

typedef __attribute__((ext_vector_type(8))) _Float16 f16x8;
typedef __attribute__((ext_vector_type(2))) _Float16 f16x2;
typedef __attribute__((ext_vector_type(4))) float f32x4;

// pack two floats into f16 pair + residual pair
struct HL { unsigned int hi, lo; };
__device__ __forceinline__ HL split2(float a, float b) {
    _Float16 ha = (_Float16)a, hb = (_Float16)b;
    _Float16 la = (_Float16)(a - (float)ha), lb = (_Float16)(b - (float)hb);
    union { _Float16 h[2]; unsigned int u; } uh, ul;
    uh.h[0] = ha; uh.h[1] = hb;
    ul.h[0] = la; ul.h[1] = lb;
    HL r; r.hi = uh.u; r.lo = ul.u; return r;
}
__device__ __forceinline__ unsigned short f2h_bits(float f) {
    union { _Float16 h; unsigned short u; } c;
    c.h = (_Float16)f;
    return c.u;
}

// ---------- 1. fused: GEMM via f16 MFMA (hi/lo split) + chunk_hist ----------
__global__ __launch_bounds__(512) void gemm_hist(
    const float* __restrict__ H, const float* __restrict__ Wg,
    unsigned short* __restrict__ Hpb, int N,
    const int* __restrict__ row, unsigned short* __restrict__ Ht,
    int E, int nchunk, int nb2, int gemmBlocks)
{
    __shared__ unsigned short Ahi[128 * 128];   // 32 KB each
    __shared__ unsigned short Alo[128 * 128];
    __shared__ unsigned short Whi[128 * 128];   // Wt[n][k]
    __shared__ unsigned short Wlo[128 * 128];
    const int tid = threadIdx.x;

    if (blockIdx.x >= gemmBlocks) {
        int* cnt = (int*)Ahi;
        const int c = blockIdx.x - gemmBlocks;
        for (int i = tid; i < nb2; i += 512) cnt[i] = 0;
        __syncthreads();
        const int e0 = c * CHUNK_E;
        const int e1 = min(e0 + CHUNK_E, E);
        for (int e = e0 + tid; e < e1; e += 512)
            atomicAdd(&cnt[row[e] >> RSH], 1);
        __syncthreads();
        for (int i = tid; i < nb2; i += 512)
            Ht[(size_t)i * nchunk + c] = (unsigned short)cnt[i];
        return;
    }

    const int rbase = blockIdx.x * 128;

    #pragma unroll
    for (int i = 0; i < 4; ++i) {
        int task = tid + 512 * i;          // 2048 tasks
        int n  = task & 127;
        int k0 = (task >> 7) * 8;
        unsigned int hi[4], lo[4];
        #pragma unroll
        for (int j = 0; j < 4; ++j) {
            float w0 = Wg[(size_t)(k0 + 2*j)     * 128 + n];
            float w1 = Wg[(size_t)(k0 + 2*j + 1) * 128 + n];
            HL s = split2(w0, w1);
            hi[j] = s.hi; lo[j] = s.lo;
        }
        int byte = (k0 * 2) ^ ((n & 7) << 4);
        *(uint4*)((char*)Whi + n * 256 + byte) = make_uint4(hi[0], hi[1], hi[2], hi[3]);
        *(uint4*)((char*)Wlo + n * 256 + byte) = make_uint4(lo[0], lo[1], lo[2], lo[3]);
    }
    #pragma unroll
    for (int i = 0; i < 8; ++i) {
        int flat = tid + 512 * i;          // 4096 float4-tasks
        int rr = flat >> 5;
        int c4  = (flat & 31) * 4;
        float4 h = make_float4(0.f, 0.f, 0.f, 0.f);
        if (rbase + rr < N)
            h = *(const float4*)&H[(size_t)(rbase + rr) * 128 + c4];
        HL s01 = split2(h.x, h.y);
        HL s23 = split2(h.z, h.w);
        uint2 vh, vl;
        vh.x = s01.hi; vh.y = s23.hi;
        vl.x = s01.lo; vl.y = s23.lo;
        int byte = (c4 * 2) ^ ((rr & 7) << 4);
        *(uint2*)((char*)Ahi + rr * 256 + byte) = vh;
        *(uint2*)((char*)Alo + rr * 256 + byte) = vl;
    }
    __syncthreads();

    const int wid = tid >> 6, lane = tid & 63;
    const int wm = wid >> 1, wn = wid & 1;
    const int lr = lane & 15, lg = lane >> 4;
    f32x4 acc[2][4] = {};

    #pragma unroll
    for (int ks = 0; ks < 4; ++ks) {
        const int kb = ks * 64 + lg * 16;
        f16x8 ahi[2], alo[2];
        #pragma unroll
        for (int mi = 0; mi < 2; ++mi) {
            int rr = wm * 32 + mi * 16 + lr;
            int sw = kb ^ ((rr & 7) << 4);
            ahi[mi] = *(const f16x8*)((char*)Ahi + rr * 256 + sw);
            alo[mi] = *(const f16x8*)((char*)Alo + rr * 256 + sw);
        }
        #pragma unroll
        for (int nf = 0; nf < 4; ++nf) {
            int n = wn * 64 + nf * 16 + lr;
            int sw = kb ^ ((n & 7) << 4);
            f16x8 bhi = *(const f16x8*)((char*)Whi + n * 256 + sw);
            f16x8 blo = *(const f16x8*)((char*)Wlo + n * 256 + sw);
            #pragma unroll
            for (int mi = 0; mi < 2; ++mi) {
                acc[mi][nf] = __builtin_amdgcn_mfma_f32_16x16x32_f16(ahi[mi], bhi, acc[mi][nf], 0, 0, 0);
                acc[mi][nf] = __builtin_amdgcn_mfma_f32_16x16x32_f16(ahi[mi], blo, acc[mi][nf], 0, 0, 0);
                acc[mi][nf] = __builtin_amdgcn_mfma_f32_16x16x32_f16(alo[mi], bhi, acc[mi][nf], 0, 0, 0);
            }
        }
    }

    #pragma unroll
    for (int mi = 0; mi < 2; ++mi) {
        #pragma unroll
        for (int nf = 0; nf < 4; ++nf) {
            int col = wn * 64 + nf * 16 + lr;
            #pragma unroll
            for (int i = 0; i < 4; ++i) {
                int rr = rbase + wm * 32 + mi * 16 + lg * 4 + i;
                if (rr < N)
                    Hpb[(size_t)rr * 128 + col] = f2h_bits(acc[mi][nf][i]);
            }
        }
    }
}

// ---------- 2b. per-bucket scan over chunks ----------
__global__ __launch_bounds__(256) void bucket_scan(
    const unsigned short* __restrict__ Ht, unsigned short* __restrict__ rel,
    int* __restrict__ totals, int nchunk)
{
    __shared__ int s[256];
    const int b = blockIdx.x, tid = threadIdx.x;
    int v = (tid < nchunk) ? (int)Ht[(size_t)b * nchunk + tid] : 0;
    s[tid] = v;
    __syncthreads();
    for (int d = 1; d < 256; d <<= 1) {
        int t = (tid >= d) ? s[tid - d] : 0;
        __syncthreads();
        s[tid] += t;
        __syncthreads();
    }
    if (tid < nchunk) rel[(size_t)b * nchunk + tid] = (unsigned short)(s[tid] - v);
    if (tid == 255) totals[b] = s[255];
}

// ---------- 2c. scan bucket totals -> bucketptr ----------
__global__ __launch_bounds__(1024) void bucket_ptr_scan(
    const int* __restrict__ totals, int* __restrict__ bucketptr, int nb2)
{
    __shared__ int s[1024];
    const int tid = threadIdx.x;
    int v = (tid < nb2) ? totals[tid] : 0;
    s[tid] = v;
    __syncthreads();
    for (int d = 1; d < 1024; d <<= 1) {
        int t = (tid >= d) ? s[tid - d] : 0;
        __syncthreads();
        s[tid] += t;
        __syncthreads();
    }
    if (tid < nb2) bucketptr[tid] = s[tid] - v;
    if (tid == nb2 - 1) bucketptr[nb2] = s[tid];
}

// ---------- 2d. atomic-free scatter: in-LDS counting sort by bucket ----------
__global__ __launch_bounds__(256) void chunk_scatter(
    const int* __restrict__ row, const int* __restrict__ col,
    const unsigned short* __restrict__ rel, const int* __restrict__ bucketptr,
    int* __restrict__ colsort, int E, int nchunk, int nb2)
{
    __shared__ int loc[1025];
    __shared__ int cur[1024];
    __shared__ int gb[1024];
    __shared__ unsigned short bid[CHUNK_E];
    __shared__ int ord[CHUNK_E];
    __shared__ int part[256];
    const int tid = threadIdx.x;
    const int c = blockIdx.x;
    const int e0 = c * CHUNK_E;
    const int tot = min(CHUNK_E, E - e0);

    for (int i = tid; i < nb2; i += 256) loc[i] = 0;
    __syncthreads();
    for (int j = tid; j < tot; j += 256)
        atomicAdd(&loc[row[e0 + j] >> RSH], 1);
    __syncthreads();

    const int base = tid * 4;
    int v[4]; int s = 0;
    #pragma unroll
    for (int i = 0; i < 4; ++i) {
        int idx = base + i;
        v[i] = (idx < nb2) ? loc[idx] : 0;
        s += v[i];
    }
    part[tid] = s;
    __syncthreads();
    for (int d = 1; d < 256; d <<= 1) {
        int t = (tid >= d) ? part[tid - d] : 0;
        __syncthreads();
        part[tid] += t;
        __syncthreads();
    }
    int run = part[tid] - s;
    #pragma unroll
    for (int i = 0; i < 4; ++i) {
        int idx = base + i;
        if (idx < nb2) { loc[idx] = run; cur[idx] = run; }
        run += v[i];
    }
    if (tid == 255) loc[nb2] = part[255];
    __syncthreads();

    for (int b = tid; b < nb2; b += 256) {
        gb[b] = bucketptr[b] + (int)rel[(size_t)b * nchunk + c];
        int st = loc[b], en = loc[b + 1];
        for (int j = st; j < en; ++j) bid[j] = (unsigned short)b;
    }
    __syncthreads();

    for (int j = tid; j < tot; j += 256) {
        int r = row[e0 + j], cc = col[e0 + j];
        int b = r >> RSH;
        int p = atomicAdd(&cur[b], 1);
        ord[p] = ((r & (RPB - 1)) << CSH) | cc;
    }
    __syncthreads();

    for (int j = tid; j < tot; j += 256) {
        int b = bid[j];
        colsort[gb[b] + (j - loc[b])] = ord[j];
    }
}

// ---------- 2e. per-bucket: derive rowptr + in-place row sort ----------
__global__ __launch_bounds__(256) void bucket_sort(
    const int* __restrict__ bucketptr, int* __restrict__ rowptr,
    int* __restrict__ colsort, int N)
{
    __shared__ int rcnt[RPB];
    __shared__ int rcur[RPB];
    __shared__ int sc[256];
    __shared__ int ord[CAP];
    const int b = blockIdx.x, tid = threadIdx.x;
    const int rbase = b << RSH;
    const int s0 = bucketptr[b];
    const int cnt = bucketptr[b + 1] - s0;

    if (tid < RPB) rcnt[tid] = 0;
    __syncthreads();
    for (int j = tid; j < cnt; j += 256)
        atomicAdd(&rcnt[colsort[s0 + j] >> CSH], 1);
    __syncthreads();

    int v = (tid < RPB) ? rcnt[tid] : 0;
    sc[tid] = v;
    __syncthreads();
    for (int d = 1; d < RPB; d <<= 1) {
        int t = (tid >= d) ? sc[tid - d] : 0;
        __syncthreads();
        sc[tid] += t;
        __syncthreads();
    }
    if (tid < RPB) {
        int ex = sc[tid] - v;
        rcur[tid] = ex;
        int r = rbase + tid;
        if (r < N) rowptr[r] = s0 + ex;
    }
    if (tid == RPB - 1) {
        int rend = min(rbase + RPB, N);
        rowptr[rend] = s0 + cnt;
    }
    __syncthreads();

    for (int j = tid; j < cnt; j += 256) {
        int rec = colsort[s0 + j];
        int p = atomicAdd(&rcur[rec >> CSH], 1);
        ord[p] = rec & CMASK;
    }
    __syncthreads();
    for (int j = tid; j < cnt; j += 256)
        colsort[s0 + j] = ord[j];
}

// ---------- 3. fused score + softmax + aggregate (f16 gathers, fdot2) ----------
union F16x8U {
    uint4 v;
    f16x2 p[4];
    _Float16 h[8];
};

__device__ __forceinline__ float dot8(const f16x2* a, const F16x8U& b) {
#if __has_builtin(__builtin_amdgcn_fdot2)
    float d = __builtin_amdgcn_fdot2(a[0], b.p[0], 0.f, false);
    d = __builtin_amdgcn_fdot2(a[1], b.p[1], d, false);
    d = __builtin_amdgcn_fdot2(a[2], b.p[2], d, false);
    d = __builtin_amdgcn_fdot2(a[3], b.p[3], d, false);
    return d;
#else
    float d = 0.f;
    #pragma unroll
    for (int k = 0; k < 8; ++k)
        d = fmaf((float)a[k >> 1][k & 1], (float)b.h[k], d);
    return d;
#endif
}

__global__ __launch_bounds__(256) void aggregate_kernel(
    const unsigned short* __restrict__ Hpb, const int* __restrict__ rowptr,
    const int* __restrict__ cols, const float* __restrict__ bias,
    float* __restrict__ out, int N)
{
    const int lane = threadIdx.x & 63;
    const int wv   = threadIdx.x >> 6;
    const int r = blockIdx.x * 4 + wv;
    if (r >= N) return;
    const int d = lane & 15;
    const int g = lane >> 4;

    const float4* bp = (const float4*)&bias[d * 8];
    const float4 b0 = bp[0], b1 = bp[1];

    F16x8U hru;
    hru.v = *(const uint4*)&Hpb[(size_t)r * 128 + d * 8];
    f16x2 hr2[4] = {hru.p[0], hru.p[1], hru.p[2], hru.p[3]};

    float acc[8] = {0.f,0.f,0.f,0.f,0.f,0.f,0.f,0.f};
    float den = 0.f;
    const int e0 = rowptr[r], e1 = rowptr[r + 1];
    const int elast = e1 - 1;

    for (int e = e0 + g; e < e1; e += 8) {
        const bool m1 = (e + 4 < e1);
        const int eb = m1 ? e + 4 : elast;
        int c0 = cols[e];
        int c1 = cols[eb];
        F16x8U u0, u1;
        u0.v = *(const uint4*)&Hpb[(size_t)c0 * 128 + d * 8];
        u1.v = *(const uint4*)&Hpb[(size_t)c1 * 128 + d * 8];

        float dot0 = dot8(hr2, u0);
        float dot1 = dot8(hr2, u1);

        dot0 += __shfl_xor(dot0, 1);
        dot1 += __shfl_xor(dot1, 1);
        dot0 += __shfl_xor(dot0, 2);
        dot1 += __shfl_xor(dot1, 2);
        dot0 += __shfl_xor(dot0, 4);
        dot1 += __shfl_xor(dot1, 4);
        dot0 += __shfl_xor(dot0, 8);
        dot1 += __shfl_xor(dot1, 8);

        float s0 = fmaxf(dot0, 0.2f * dot0);
        float s1 = fmaxf(dot1, 0.2f * dot1);
        float ex0 = __expf(s0);
        float ex1 = m1 ? __expf(s1) : 0.f;
        den += ex0 + ex1;
        #pragma unroll
        for (int k = 0; k < 8; ++k) {
            acc[k] = fmaf((float)u0.h[k], ex0, acc[k]);   // v_fma_mix_f32
            acc[k] = fmaf((float)u1.h[k], ex1, acc[k]);
        }
    }

    #pragma unroll
    for (int k = 0; k < 8; ++k) {
        acc[k] += __shfl_xor(acc[k], 16);
        acc[k] += __shfl_xor(acc[k], 32);
    }
    den += __shfl_xor(den, 16);
    den += __shfl_xor(den, 32);

    if (g == 0) {
        float inv = 1.f / (den + 1e-10f);
        float4 o0, o1;
        o0.x = fmaf(acc[0], inv, b0.x);
        o0.y = fmaf(acc[1], inv, b0.y);
        o0.z = fmaf(acc[2], inv, b0.z);
        o0.w = fmaf(acc[3], inv, b0.w);
        o1.x = fmaf(acc[4], inv, b1.x);
        o1.y = fmaf(acc[5], inv, b1.y);
        o1.z = fmaf(acc[6], inv, b1.z);
        o1.w = fmaf(acc[7], inv, b1.w);
        float4* op = (float4*)&out[(size_t)r * 128 + d * 8];
        op[0] = o0;
        op[1] = o1;
    }
}

extern "C" void kernel_launch(void* const* d_in, const int* in_sizes, int n_in,
                              void* d_out, int out_size, void* d_ws, size_t ws_size,
                              hipStream_t stream)
{
    const float* H    = (const float*)d_in[0];
    const float* W    = (const float*)d_in[1];
    const float* bias = (const float*)d_in[2];
    const int*   row  = (const int*)d_in[3];
    const int*   col  = (const int*)d_in[4];
    const int N = in_sizes[0] / 128;
    const int E = in_sizes[3];

    const int nchunk = (E + CHUNK_E - 1) / CHUNK_E;   // 196
    const int nb2    = (N + RPB - 1) / RPB;           // 782

    auto align = [](size_t x) { return (x + 255) & ~(size_t)255; };

    char* ws = (char*)d_ws;
    size_t off = 0;
    unsigned short* Hpb       = (unsigned short*)(ws + off); off = align(off + (size_t)N * 128 * 2);
    unsigned short* Ht        = (unsigned short*)(ws + off); off = align(off + (size_t)nb2 * nchunk * 2);
    unsigned short* rel       = (unsigned short*)(ws + off); off = align(off + (size_t)nb2 * nchunk * 2);
    int*            totals    = (int*)(ws + off);            off = align(off + (size_t)nb2 * 4);
    int*            bucketptr = (int*)(ws + off);            off = align(off + (size_t)(nb2 + 1) * 4);
    int*            rowptr    = (int*)(ws + off);            off = align(off + (size_t)(N + 1) * 4);
    int*            colsort   = (int*)(ws + off);

    const int gemmBlocks = (N + 127) / 128;

    gemm_hist<<<gemmBlocks + nchunk, 512, 0, stream>>>(H, W, Hpb, N,
                                                       row, Ht, E, nchunk, nb2,
                                                       gemmBlocks);
    bucket_scan<<<nb2, 256, 0, stream>>>(Ht, rel, totals, nchunk);
    bucket_ptr_scan<<<1, 1024, 0, stream>>>(totals, bucketptr, nb2);
    chunk_scatter<<<nchunk, 256, 0, stream>>>(row, col, rel, bucketptr,
                                              colsort, E, nchunk, nb2);
    bucket_sort<<<nb2, 256, 0, stream>>>(bucketptr, rowptr, colsort, N);
    aggregate_kernel<<<(N + 3) / 4, 256, 0, stream>>>(Hpb, rowptr, colsort, bias,
                                                      (float*)d_out, N);
}

// Round 15
// 134.769 us; speedup vs baseline: 1.2826x; 1.0304x over previous
//
#include <hip/hip_runtime.h>
#include <hip/hip_bf16.h>

#define RSH 7                  // 128 rows per bucket
#define RPB (1 << RSH)
#define CSH 17                 // col bits in packed record (N < 131072)
#define CMASK ((1 << CSH) - 1)
#define CHUNK_E 8192           // edges per chunk block
#define CAP 4096               // max records per bucket (mean ~2048, 45 sigma)
#define NBMAX 1024

typedef __attribute__((ext_vector_type(8))) _Float16 f16x8;
typedef __attribute__((ext_vector_type(2))) _Float16 f16x2;
typedef __attribute__((ext_vector_type(4))) float f32x4;

// pack two floats into f16 pair + residual pair
struct HL { unsigned int hi, lo; };
__device__ __forceinline__ HL split2(float a, float b) {
    _Float16 ha = (_Float16)a, hb = (_Float16)b;
    _Float16 la = (_Float16)(a - (float)ha), lb = (_Float16)(b - (float)hb);
    union { _Float16 h[2]; unsigned int u; } uh, ul;
    uh.h[0] = ha; uh.h[1] = hb;
    ul.h[0] = la; ul.h[1] = lb;
    HL r; r.hi = uh.u; r.lo = ul.u; return r;
}
__device__ __forceinline__ unsigned short f2h_bits(float f) {
    union { _Float16 h; unsigned short u; } c;
    c.h = (_Float16)f;
    return c.u;
}

// ---------- 0. W pre-split: build the swizzled LDS image once ----------
__global__ __launch_bounds__(256) void wsplit(
    const float* __restrict__ Wg, unsigned int* __restrict__ WhiG,
    unsigned int* __restrict__ WloG)
{
    int task = blockIdx.x * 256 + threadIdx.x;   // 2048 tasks
    if (task >= 2048) return;
    int n  = task & 127;
    int k0 = (task >> 7) * 8;
    unsigned int hi[4], lo[4];
    #pragma unroll
    for (int j = 0; j < 4; ++j) {
        float w0 = Wg[(size_t)(k0 + 2*j)     * 128 + n];
        float w1 = Wg[(size_t)(k0 + 2*j + 1) * 128 + n];
        HL s = split2(w0, w1);
        hi[j] = s.hi; lo[j] = s.lo;
    }
    int byte = (k0 * 2) ^ ((n & 7) << 4);
    *(uint4*)((char*)WhiG + n * 256 + byte) = make_uint4(hi[0], hi[1], hi[2], hi[3]);
    *(uint4*)((char*)WloG + n * 256 + byte) = make_uint4(lo[0], lo[1], lo[2], lo[3]);
}

// ---------- 1. fused: GEMM via f16 MFMA (hi/lo split) + chunk_hist ----------
__global__ __launch_bounds__(512) void gemm_hist(
    const float* __restrict__ H,
    const unsigned int* __restrict__ WhiG, const unsigned int* __restrict__ WloG,
    unsigned short* __restrict__ Hpb, int N,
    const int* __restrict__ row, unsigned short* __restrict__ Ht,
    int E, int nchunk, int nb2, int gemmBlocks)
{
    __shared__ unsigned short Ahi[128 * 128];   // 32 KB each
    __shared__ unsigned short Alo[128 * 128];
    __shared__ unsigned short Whi[128 * 128];   // pre-split image
    __shared__ unsigned short Wlo[128 * 128];
    const int tid = threadIdx.x;

    if (blockIdx.x >= gemmBlocks) {
        int* cnt = (int*)Ahi;
        const int c = blockIdx.x - gemmBlocks;
        for (int i = tid; i < nb2; i += 512) cnt[i] = 0;
        __syncthreads();
        const int e0 = c * CHUNK_E;
        const int e1 = min(e0 + CHUNK_E, E);
        for (int e = e0 + tid; e < e1; e += 512)
            atomicAdd(&cnt[row[e] >> RSH], 1);
        __syncthreads();
        for (int i = tid; i < nb2; i += 512)
            Ht[(size_t)i * nchunk + c] = (unsigned short)cnt[i];
        return;
    }

    const int rbase = blockIdx.x * 128;

    // stage pre-split W: verbatim 2x32KB copy
    #pragma unroll
    for (int i = 0; i < 4; ++i) {
        int idx = tid + 512 * i;               // 2048 uint4 per buffer
        ((uint4*)Whi)[idx] = ((const uint4*)WhiG)[idx];
        ((uint4*)Wlo)[idx] = ((const uint4*)WloG)[idx];
    }
    #pragma unroll
    for (int i = 0; i < 8; ++i) {
        int flat = tid + 512 * i;          // 4096 float4-tasks
        int rr = flat >> 5;
        int c4  = (flat & 31) * 4;
        float4 h = make_float4(0.f, 0.f, 0.f, 0.f);
        if (rbase + rr < N)
            h = *(const float4*)&H[(size_t)(rbase + rr) * 128 + c4];
        HL s01 = split2(h.x, h.y);
        HL s23 = split2(h.z, h.w);
        uint2 vh, vl;
        vh.x = s01.hi; vh.y = s23.hi;
        vl.x = s01.lo; vl.y = s23.lo;
        int byte = (c4 * 2) ^ ((rr & 7) << 4);
        *(uint2*)((char*)Ahi + rr * 256 + byte) = vh;
        *(uint2*)((char*)Alo + rr * 256 + byte) = vl;
    }
    __syncthreads();

    const int wid = tid >> 6, lane = tid & 63;
    const int wm = wid >> 1, wn = wid & 1;
    const int lr = lane & 15, lg = lane >> 4;
    f32x4 acc[2][4] = {};

    #pragma unroll
    for (int ks = 0; ks < 4; ++ks) {
        const int kb = ks * 64 + lg * 16;
        f16x8 ahi[2], alo[2];
        #pragma unroll
        for (int mi = 0; mi < 2; ++mi) {
            int rr = wm * 32 + mi * 16 + lr;
            int sw = kb ^ ((rr & 7) << 4);
            ahi[mi] = *(const f16x8*)((char*)Ahi + rr * 256 + sw);
            alo[mi] = *(const f16x8*)((char*)Alo + rr * 256 + sw);
        }
        #pragma unroll
        for (int nf = 0; nf < 4; ++nf) {
            int n = wn * 64 + nf * 16 + lr;
            int sw = kb ^ ((n & 7) << 4);
            f16x8 bhi = *(const f16x8*)((char*)Whi + n * 256 + sw);
            f16x8 blo = *(const f16x8*)((char*)Wlo + n * 256 + sw);
            #pragma unroll
            for (int mi = 0; mi < 2; ++mi) {
                acc[mi][nf] = __builtin_amdgcn_mfma_f32_16x16x32_f16(ahi[mi], bhi, acc[mi][nf], 0, 0, 0);
                acc[mi][nf] = __builtin_amdgcn_mfma_f32_16x16x32_f16(ahi[mi], blo, acc[mi][nf], 0, 0, 0);
                acc[mi][nf] = __builtin_amdgcn_mfma_f32_16x16x32_f16(alo[mi], bhi, acc[mi][nf], 0, 0, 0);
            }
        }
    }

    #pragma unroll
    for (int mi = 0; mi < 2; ++mi) {
        #pragma unroll
        for (int nf = 0; nf < 4; ++nf) {
            int col = wn * 64 + nf * 16 + lr;
            #pragma unroll
            for (int i = 0; i < 4; ++i) {
                int rr = rbase + wm * 32 + mi * 16 + lg * 4 + i;
                if (rr < N)
                    Hpb[(size_t)rr * 128 + col] = f2h_bits(acc[mi][nf][i]);
            }
        }
    }
}

// ---------- 2b. per-bucket scan over chunks ----------
__global__ __launch_bounds__(256) void bucket_scan(
    const unsigned short* __restrict__ Ht, unsigned short* __restrict__ rel,
    int* __restrict__ totals, int nchunk)
{
    __shared__ int s[256];
    const int b = blockIdx.x, tid = threadIdx.x;
    int v = (tid < nchunk) ? (int)Ht[(size_t)b * nchunk + tid] : 0;
    s[tid] = v;
    __syncthreads();
    for (int d = 1; d < 256; d <<= 1) {
        int t = (tid >= d) ? s[tid - d] : 0;
        __syncthreads();
        s[tid] += t;
        __syncthreads();
    }
    if (tid < nchunk) rel[(size_t)b * nchunk + tid] = (unsigned short)(s[tid] - v);
    if (tid == 255) totals[b] = s[255];
}

// ---------- 2c. scan bucket totals -> bucketptr ----------
__global__ __launch_bounds__(1024) void bucket_ptr_scan(
    const int* __restrict__ totals, int* __restrict__ bucketptr, int nb2)
{
    __shared__ int s[1024];
    const int tid = threadIdx.x;
    int v = (tid < nb2) ? totals[tid] : 0;
    s[tid] = v;
    __syncthreads();
    for (int d = 1; d < 1024; d <<= 1) {
        int t = (tid >= d) ? s[tid - d] : 0;
        __syncthreads();
        s[tid] += t;
        __syncthreads();
    }
    if (tid < nb2) bucketptr[tid] = s[tid] - v;
    if (tid == nb2 - 1) bucketptr[nb2] = s[tid];
}

// ---------- 2d. single-pass scatter: exact per-chunk offsets, 8KB LDS ----------
__global__ __launch_bounds__(256) void chunk_scatter(
    const int* __restrict__ row, const int* __restrict__ col,
    const unsigned short* __restrict__ rel, const int* __restrict__ bucketptr,
    int* __restrict__ colsort, int E, int nchunk, int nb2)
{
    __shared__ int cur[NBMAX];
    __shared__ int gb[NBMAX];
    const int tid = threadIdx.x;
    const int c = blockIdx.x;
    const int e0 = c * CHUNK_E;
    const int tot = min(CHUNK_E, E - e0);

    for (int b = tid; b < nb2; b += 256) {
        cur[b] = 0;
        gb[b] = bucketptr[b] + (int)rel[(size_t)b * nchunk + c];
    }
    __syncthreads();

    for (int j = tid; j < tot; j += 256) {
        int r = row[e0 + j], cc = col[e0 + j];
        int b = r >> RSH;
        int p = atomicAdd(&cur[b], 1);
        colsort[gb[b] + p] = ((r & (RPB - 1)) << CSH) | cc;
    }
}

// ---------- 2e. per-bucket: derive rowptr + in-place row sort ----------
__global__ __launch_bounds__(256) void bucket_sort(
    const int* __restrict__ bucketptr, int* __restrict__ rowptr,
    int* __restrict__ colsort, int N)
{
    __shared__ int rcnt[RPB];
    __shared__ int rcur[RPB];
    __shared__ int sc[256];
    __shared__ int ord[CAP];
    const int b = blockIdx.x, tid = threadIdx.x;
    const int rbase = b << RSH;
    const int s0 = bucketptr[b];
    const int cnt = bucketptr[b + 1] - s0;

    if (tid < RPB) rcnt[tid] = 0;
    __syncthreads();
    for (int j = tid; j < cnt; j += 256)
        atomicAdd(&rcnt[colsort[s0 + j] >> CSH], 1);
    __syncthreads();

    int v = (tid < RPB) ? rcnt[tid] : 0;
    sc[tid] = v;
    __syncthreads();
    for (int d = 1; d < RPB; d <<= 1) {
        int t = (tid >= d) ? sc[tid - d] : 0;
        __syncthreads();
        sc[tid] += t;
        __syncthreads();
    }
    if (tid < RPB) {
        int ex = sc[tid] - v;
        rcur[tid] = ex;
        int r = rbase + tid;
        if (r < N) rowptr[r] = s0 + ex;
    }
    if (tid == RPB - 1) {
        int rend = min(rbase + RPB, N);
        rowptr[rend] = s0 + cnt;
    }
    __syncthreads();

    for (int j = tid; j < cnt; j += 256) {
        int rec = colsort[s0 + j];
        int p = atomicAdd(&rcur[rec >> CSH], 1);
        ord[p] = rec & CMASK;
    }
    __syncthreads();
    for (int j = tid; j < cnt; j += 256)
        colsort[s0 + j] = ord[j];
}

// ---------- 3. fused score + softmax + aggregate (f16 gathers, fdot2) ----------
union F16x8U {
    uint4 v;
    f16x2 p[4];
    _Float16 h[8];
};

__device__ __forceinline__ float dot8(const f16x2* a, const F16x8U& b) {
#if __has_builtin(__builtin_amdgcn_fdot2)
    float d = __builtin_amdgcn_fdot2(a[0], b.p[0], 0.f, false);
    d = __builtin_amdgcn_fdot2(a[1], b.p[1], d, false);
    d = __builtin_amdgcn_fdot2(a[2], b.p[2], d, false);
    d = __builtin_amdgcn_fdot2(a[3], b.p[3], d, false);
    return d;
#else
    float d = 0.f;
    #pragma unroll
    for (int k = 0; k < 8; ++k)
        d = fmaf((float)a[k >> 1][k & 1], (float)b.h[k], d);
    return d;
#endif
}

__global__ __launch_bounds__(256) void aggregate_kernel(
    const unsigned short* __restrict__ Hpb, const int* __restrict__ rowptr,
    const int* __restrict__ cols, const float* __restrict__ bias,
    float* __restrict__ out, int N)
{
    const int lane = threadIdx.x & 63;
    const int wv   = threadIdx.x >> 6;
    const int r = blockIdx.x * 4 + wv;
    if (r >= N) return;
    const int d = lane & 15;
    const int g = lane >> 4;

    const float4* bp = (const float4*)&bias[d * 8];
    const float4 b0 = bp[0], b1 = bp[1];

    F16x8U hru;
    hru.v = *(const uint4*)&Hpb[(size_t)r * 128 + d * 8];
    f16x2 hr2[4] = {hru.p[0], hru.p[1], hru.p[2], hru.p[3]};

    float acc[8] = {0.f,0.f,0.f,0.f,0.f,0.f,0.f,0.f};
    float den = 0.f;
    const int e0 = rowptr[r], e1 = rowptr[r + 1];
    const int elast = e1 - 1;

    for (int e = e0 + g; e < e1; e += 8) {
        const bool m1 = (e + 4 < e1);
        const int eb = m1 ? e + 4 : elast;
        int c0 = cols[e];
        int c1 = cols[eb];
        F16x8U u0, u1;
        u0.v = *(const uint4*)&Hpb[(size_t)c0 * 128 + d * 8];
        u1.v = *(const uint4*)&Hpb[(size_t)c1 * 128 + d * 8];

        float dot0 = dot8(hr2, u0);
        float dot1 = dot8(hr2, u1);

        dot0 += __shfl_xor(dot0, 1);
        dot1 += __shfl_xor(dot1, 1);
        dot0 += __shfl_xor(dot0, 2);
        dot1 += __shfl_xor(dot1, 2);
        dot0 += __shfl_xor(dot0, 4);
        dot1 += __shfl_xor(dot1, 4);
        dot0 += __shfl_xor(dot0, 8);
        dot1 += __shfl_xor(dot1, 8);

        float s0 = fmaxf(dot0, 0.2f * dot0);
        float s1 = fmaxf(dot1, 0.2f * dot1);
        float ex0 = __expf(s0);
        float ex1 = m1 ? __expf(s1) : 0.f;
        den += ex0 + ex1;
        #pragma unroll
        for (int k = 0; k < 8; ++k) {
            acc[k] = fmaf((float)u0.h[k], ex0, acc[k]);   // v_fma_mix_f32
            acc[k] = fmaf((float)u1.h[k], ex1, acc[k]);
        }
    }

    #pragma unroll
    for (int k = 0; k < 8; ++k) {
        acc[k] += __shfl_xor(acc[k], 16);
        acc[k] += __shfl_xor(acc[k], 32);
    }
    den += __shfl_xor(den, 16);
    den += __shfl_xor(den, 32);

    if (g == 0) {
        float inv = 1.f / (den + 1e-10f);
        float4 o0, o1;
        o0.x = fmaf(acc[0], inv, b0.x);
        o0.y = fmaf(acc[1], inv, b0.y);
        o0.z = fmaf(acc[2], inv, b0.z);
        o0.w = fmaf(acc[3], inv, b0.w);
        o1.x = fmaf(acc[4], inv, b1.x);
        o1.y = fmaf(acc[5], inv, b1.y);
        o1.z = fmaf(acc[6], inv, b1.z);
        o1.w = fmaf(acc[7], inv, b1.w);
        float4* op = (float4*)&out[(size_t)r * 128 + d * 8];
        op[0] = o0;
        op[1] = o1;
    }
}

extern "C" void kernel_launch(void* const* d_in, const int* in_sizes, int n_in,
                              void* d_out, int out_size, void* d_ws, size_t ws_size,
                              hipStream_t stream)
{
    const float* H    = (const float*)d_in[0];
    const float* W    = (const float*)d_in[1];
    const float* bias = (const float*)d_in[2];
    const int*   row  = (const int*)d_in[3];
    const int*   col  = (const int*)d_in[4];
    const int N = in_sizes[0] / 128;
    const int E = in_sizes[3];

    const int nchunk = (E + CHUNK_E - 1) / CHUNK_E;   // 196
    const int nb2    = (N + RPB - 1) / RPB;           // 782

    auto align = [](size_t x) { return (x + 255) & ~(size_t)255; };

    char* ws = (char*)d_ws;
    size_t off = 0;
    unsigned short* Hpb       = (unsigned short*)(ws + off); off = align(off + (size_t)N * 128 * 2);
    unsigned short* Ht        = (unsigned short*)(ws + off); off = align(off + (size_t)nb2 * nchunk * 2);
    unsigned short* rel       = (unsigned short*)(ws + off); off = align(off + (size_t)nb2 * nchunk * 2);
    int*            totals    = (int*)(ws + off);            off = align(off + (size_t)nb2 * 4);
    int*            bucketptr = (int*)(ws + off);            off = align(off + (size_t)(nb2 + 1) * 4);
    int*            rowptr    = (int*)(ws + off);            off = align(off + (size_t)(N + 1) * 4);
    unsigned int*   WhiG      = (unsigned int*)(ws + off);   off = align(off + 8192 * 4);
    unsigned int*   WloG      = (unsigned int*)(ws + off);   off = align(off + 8192 * 4);
    int*            colsort   = (int*)(ws + off);

    const int gemmBlocks = (N + 127) / 128;

    wsplit<<<8, 256, 0, stream>>>(W, WhiG, WloG);
    gemm_hist<<<gemmBlocks + nchunk, 512, 0, stream>>>(H, WhiG, WloG, Hpb, N,
                                                       row, Ht, E, nchunk, nb2,
                                                       gemmBlocks);
    bucket_scan<<<nb2, 256, 0, stream>>>(Ht, rel, totals, nchunk);
    bucket_ptr_scan<<<1, 1024, 0, stream>>>(totals, bucketptr, nb2);
    chunk_scatter<<<nchunk, 256, 0, stream>>>(row, col, rel, bucketptr,
                                              colsort, E, nchunk, nb2);
    bucket_sort<<<nb2, 256, 0, stream>>>(bucketptr, rowptr, colsort, N);
    aggregate_kernel<<<(N + 3) / 4, 256, 0, stream>>>(Hpb, rowptr, colsort, bias,
                                                      (float*)d_out, N);
}

// Round 16
// 122.697 us; speedup vs baseline: 1.4088x; 1.0984x over previous
//
#include <hip/hip_runtime.h>
#include <hip/hip_bf16.h>

#define RSH 7                  // 128 rows per bucket
#define RPB (1 << RSH)
#define CSH 17                 // col bits in packed record (N < 131072)
#define CMASK ((1 << CSH) - 1)
#define CHUNK_E 8192           // edges per chunk block
#define CAP 4096               // max records per bucket (mean ~2048, 45 sigma)
#define NBMAX 1024

typedef __attribute__((ext_vector_type(8))) _Float16 f16x8;
typedef __attribute__((ext_vector_type(2))) _Float16 f16x2;
typedef __attribute__((ext_vector_type(4))) float f32x4;

__device__ __forceinline__ unsigned int pack2h(float a, float b) {
    union { _Float16 h[2]; unsigned int u; } c;
    c.h[0] = (_Float16)a; c.h[1] = (_Float16)b;
    return c.u;
}
__device__ __forceinline__ unsigned short f2h_bits(float f) {
    union { _Float16 h; unsigned short u; } c;
    c.h = (_Float16)f;
    return c.u;
}

// ---------- 0. W pre-convert: build the swizzled f16 LDS image once ----------
__global__ __launch_bounds__(256) void wsplit(
    const float* __restrict__ Wg, unsigned int* __restrict__ WhiG)
{
    int task = blockIdx.x * 256 + threadIdx.x;   // 2048 tasks
    if (task >= 2048) return;
    int n  = task & 127;
    int k0 = (task >> 7) * 8;
    unsigned int hi[4];
    #pragma unroll
    for (int j = 0; j < 4; ++j) {
        float w0 = Wg[(size_t)(k0 + 2*j)     * 128 + n];
        float w1 = Wg[(size_t)(k0 + 2*j + 1) * 128 + n];
        hi[j] = pack2h(w0, w1);
    }
    int byte = (k0 * 2) ^ ((n & 7) << 4);
    *(uint4*)((char*)WhiG + n * 256 + byte) = make_uint4(hi[0], hi[1], hi[2], hi[3]);
}

// ---------- 1. fused: GEMM via single-f16 MFMA + chunk_hist ----------
__global__ __launch_bounds__(512) void gemm_hist(
    const float* __restrict__ H, const unsigned int* __restrict__ WhiG,
    unsigned short* __restrict__ Hpb, int N,
    const int* __restrict__ row, unsigned short* __restrict__ Ht,
    int E, int nchunk, int nb2, int gemmBlocks)
{
    __shared__ unsigned short Ahi[128 * 128];   // 32 KB
    __shared__ unsigned short Whi[128 * 128];   // 32 KB (pre-converted image)
    const int tid = threadIdx.x;

    if (blockIdx.x >= gemmBlocks) {
        int* cnt = (int*)Ahi;
        const int c = blockIdx.x - gemmBlocks;
        for (int i = tid; i < nb2; i += 512) cnt[i] = 0;
        __syncthreads();
        const int e0 = c * CHUNK_E;
        const int e1 = min(e0 + CHUNK_E, E);
        for (int e = e0 + tid; e < e1; e += 512)
            atomicAdd(&cnt[row[e] >> RSH], 1);
        __syncthreads();
        for (int i = tid; i < nb2; i += 512)
            Ht[(size_t)i * nchunk + c] = (unsigned short)cnt[i];
        return;
    }

    const int rbase = blockIdx.x * 128;

    // stage pre-converted W: verbatim 32KB copy
    #pragma unroll
    for (int i = 0; i < 4; ++i) {
        int idx = tid + 512 * i;               // 2048 uint4
        ((uint4*)Whi)[idx] = ((const uint4*)WhiG)[idx];
    }
    // stage H rows as f16
    #pragma unroll
    for (int i = 0; i < 8; ++i) {
        int flat = tid + 512 * i;          // 4096 float4-tasks
        int rr = flat >> 5;
        int c4  = (flat & 31) * 4;
        float4 h = make_float4(0.f, 0.f, 0.f, 0.f);
        if (rbase + rr < N)
            h = *(const float4*)&H[(size_t)(rbase + rr) * 128 + c4];
        uint2 vh;
        vh.x = pack2h(h.x, h.y);
        vh.y = pack2h(h.z, h.w);
        int byte = (c4 * 2) ^ ((rr & 7) << 4);
        *(uint2*)((char*)Ahi + rr * 256 + byte) = vh;
    }
    __syncthreads();

    const int wid = tid >> 6, lane = tid & 63;
    const int wm = wid >> 1, wn = wid & 1;
    const int lr = lane & 15, lg = lane >> 4;
    f32x4 acc[2][4] = {};

    #pragma unroll
    for (int ks = 0; ks < 4; ++ks) {
        const int kb = ks * 64 + lg * 16;
        f16x8 ahi[2];
        #pragma unroll
        for (int mi = 0; mi < 2; ++mi) {
            int rr = wm * 32 + mi * 16 + lr;
            int sw = kb ^ ((rr & 7) << 4);
            ahi[mi] = *(const f16x8*)((char*)Ahi + rr * 256 + sw);
        }
        #pragma unroll
        for (int nf = 0; nf < 4; ++nf) {
            int n = wn * 64 + nf * 16 + lr;
            int sw = kb ^ ((n & 7) << 4);
            f16x8 bhi = *(const f16x8*)((char*)Whi + n * 256 + sw);
            #pragma unroll
            for (int mi = 0; mi < 2; ++mi)
                acc[mi][nf] = __builtin_amdgcn_mfma_f32_16x16x32_f16(ahi[mi], bhi, acc[mi][nf], 0, 0, 0);
        }
    }

    #pragma unroll
    for (int mi = 0; mi < 2; ++mi) {
        #pragma unroll
        for (int nf = 0; nf < 4; ++nf) {
            int col = wn * 64 + nf * 16 + lr;
            #pragma unroll
            for (int i = 0; i < 4; ++i) {
                int rr = rbase + wm * 32 + mi * 16 + lg * 4 + i;
                if (rr < N)
                    Hpb[(size_t)rr * 128 + col] = f2h_bits(acc[mi][nf][i]);
            }
        }
    }
}

// ---------- 2b. per-bucket scan over chunks ----------
__global__ __launch_bounds__(256) void bucket_scan(
    const unsigned short* __restrict__ Ht, unsigned short* __restrict__ rel,
    int* __restrict__ totals, int nchunk)
{
    __shared__ int s[256];
    const int b = blockIdx.x, tid = threadIdx.x;
    int v = (tid < nchunk) ? (int)Ht[(size_t)b * nchunk + tid] : 0;
    s[tid] = v;
    __syncthreads();
    for (int d = 1; d < 256; d <<= 1) {
        int t = (tid >= d) ? s[tid - d] : 0;
        __syncthreads();
        s[tid] += t;
        __syncthreads();
    }
    if (tid < nchunk) rel[(size_t)b * nchunk + tid] = (unsigned short)(s[tid] - v);
    if (tid == 255) totals[b] = s[255];
}

// ---------- 2c. scan bucket totals -> bucketptr ----------
__global__ __launch_bounds__(1024) void bucket_ptr_scan(
    const int* __restrict__ totals, int* __restrict__ bucketptr, int nb2)
{
    __shared__ int s[1024];
    const int tid = threadIdx.x;
    int v = (tid < nb2) ? totals[tid] : 0;
    s[tid] = v;
    __syncthreads();
    for (int d = 1; d < 1024; d <<= 1) {
        int t = (tid >= d) ? s[tid - d] : 0;
        __syncthreads();
        s[tid] += t;
        __syncthreads();
    }
    if (tid < nb2) bucketptr[tid] = s[tid] - v;
    if (tid == nb2 - 1) bucketptr[nb2] = s[tid];
}

// ---------- 2d. single-pass scatter: exact per-chunk offsets, 8KB LDS ----------
__global__ __launch_bounds__(256) void chunk_scatter(
    const int* __restrict__ row, const int* __restrict__ col,
    const unsigned short* __restrict__ rel, const int* __restrict__ bucketptr,
    int* __restrict__ colsort, int E, int nchunk, int nb2)
{
    __shared__ int cur[NBMAX];
    __shared__ int gb[NBMAX];
    const int tid = threadIdx.x;
    const int c = blockIdx.x;
    const int e0 = c * CHUNK_E;
    const int tot = min(CHUNK_E, E - e0);

    for (int b = tid; b < nb2; b += 256) {
        cur[b] = 0;
        gb[b] = bucketptr[b] + (int)rel[(size_t)b * nchunk + c];
    }
    __syncthreads();

    for (int j = tid; j < tot; j += 256) {
        int r = row[e0 + j], cc = col[e0 + j];
        int b = r >> RSH;
        int p = atomicAdd(&cur[b], 1);
        colsort[gb[b] + p] = ((r & (RPB - 1)) << CSH) | cc;
    }
}

// ---------- 2e. per-bucket: derive rowptr + in-place row sort ----------
__global__ __launch_bounds__(256) void bucket_sort(
    const int* __restrict__ bucketptr, int* __restrict__ rowptr,
    int* __restrict__ colsort, int N)
{
    __shared__ int rcnt[RPB];
    __shared__ int rcur[RPB];
    __shared__ int sc[256];
    __shared__ int ord[CAP];
    const int b = blockIdx.x, tid = threadIdx.x;
    const int rbase = b << RSH;
    const int s0 = bucketptr[b];
    const int cnt = bucketptr[b + 1] - s0;

    if (tid < RPB) rcnt[tid] = 0;
    __syncthreads();
    for (int j = tid; j < cnt; j += 256)
        atomicAdd(&rcnt[colsort[s0 + j] >> CSH], 1);
    __syncthreads();

    int v = (tid < RPB) ? rcnt[tid] : 0;
    sc[tid] = v;
    __syncthreads();
    for (int d = 1; d < RPB; d <<= 1) {
        int t = (tid >= d) ? sc[tid - d] : 0;
        __syncthreads();
        sc[tid] += t;
        __syncthreads();
    }
    if (tid < RPB) {
        int ex = sc[tid] - v;
        rcur[tid] = ex;
        int r = rbase + tid;
        if (r < N) rowptr[r] = s0 + ex;
    }
    if (tid == RPB - 1) {
        int rend = min(rbase + RPB, N);
        rowptr[rend] = s0 + cnt;
    }
    __syncthreads();

    for (int j = tid; j < cnt; j += 256) {
        int rec = colsort[s0 + j];
        int p = atomicAdd(&rcur[rec >> CSH], 1);
        ord[p] = rec & CMASK;
    }
    __syncthreads();
    for (int j = tid; j < cnt; j += 256)
        colsort[s0 + j] = ord[j];
}

// ---------- 3. fused score + softmax + aggregate (f16 gathers, fdot2) ----------
union F16x8U {
    uint4 v;
    f16x2 p[4];
    _Float16 h[8];
};

__device__ __forceinline__ float dot8(const f16x2* a, const F16x8U& b) {
#if __has_builtin(__builtin_amdgcn_fdot2)
    float d = __builtin_amdgcn_fdot2(a[0], b.p[0], 0.f, false);
    d = __builtin_amdgcn_fdot2(a[1], b.p[1], d, false);
    d = __builtin_amdgcn_fdot2(a[2], b.p[2], d, false);
    d = __builtin_amdgcn_fdot2(a[3], b.p[3], d, false);
    return d;
#else
    float d = 0.f;
    #pragma unroll
    for (int k = 0; k < 8; ++k)
        d = fmaf((float)a[k >> 1][k & 1], (float)b.h[k], d);
    return d;
#endif
}

__global__ __launch_bounds__(256) void aggregate_kernel(
    const unsigned short* __restrict__ Hpb, const int* __restrict__ rowptr,
    const int* __restrict__ cols, const float* __restrict__ bias,
    float* __restrict__ out, int N)
{
    const int lane = threadIdx.x & 63;
    const int wv   = threadIdx.x >> 6;
    const int r = blockIdx.x * 4 + wv;
    if (r >= N) return;
    const int d = lane & 15;
    const int g = lane >> 4;

    const float4* bp = (const float4*)&bias[d * 8];
    const float4 b0 = bp[0], b1 = bp[1];

    F16x8U hru;
    hru.v = *(const uint4*)&Hpb[(size_t)r * 128 + d * 8];
    f16x2 hr2[4] = {hru.p[0], hru.p[1], hru.p[2], hru.p[3]};

    float acc[8] = {0.f,0.f,0.f,0.f,0.f,0.f,0.f,0.f};
    float den = 0.f;
    const int e0 = rowptr[r], e1 = rowptr[r + 1];
    const int elast = e1 - 1;

    for (int e = e0 + g; e < e1; e += 8) {
        const bool m1 = (e + 4 < e1);
        const int eb = m1 ? e + 4 : elast;
        int c0 = cols[e];
        int c1 = cols[eb];
        F16x8U u0, u1;
        u0.v = *(const uint4*)&Hpb[(size_t)c0 * 128 + d * 8];
        u1.v = *(const uint4*)&Hpb[(size_t)c1 * 128 + d * 8];

        float dot0 = dot8(hr2, u0);
        float dot1 = dot8(hr2, u1);

        dot0 += __shfl_xor(dot0, 1);
        dot1 += __shfl_xor(dot1, 1);
        dot0 += __shfl_xor(dot0, 2);
        dot1 += __shfl_xor(dot1, 2);
        dot0 += __shfl_xor(dot0, 4);
        dot1 += __shfl_xor(dot1, 4);
        dot0 += __shfl_xor(dot0, 8);
        dot1 += __shfl_xor(dot1, 8);

        float s0 = fmaxf(dot0, 0.2f * dot0);
        float s1 = fmaxf(dot1, 0.2f * dot1);
        float ex0 = __expf(s0);
        float ex1 = m1 ? __expf(s1) : 0.f;
        den += ex0 + ex1;
        #pragma unroll
        for (int k = 0; k < 8; ++k) {
            acc[k] = fmaf((float)u0.h[k], ex0, acc[k]);   // v_fma_mix_f32
            acc[k] = fmaf((float)u1.h[k], ex1, acc[k]);
        }
    }

    #pragma unroll
    for (int k = 0; k < 8; ++k) {
        acc[k] += __shfl_xor(acc[k], 16);
        acc[k] += __shfl_xor(acc[k], 32);
    }
    den += __shfl_xor(den, 16);
    den += __shfl_xor(den, 32);

    if (g == 0) {
        float inv = 1.f / (den + 1e-10f);
        float4 o0, o1;
        o0.x = fmaf(acc[0], inv, b0.x);
        o0.y = fmaf(acc[1], inv, b0.y);
        o0.z = fmaf(acc[2], inv, b0.z);
        o0.w = fmaf(acc[3], inv, b0.w);
        o1.x = fmaf(acc[4], inv, b1.x);
        o1.y = fmaf(acc[5], inv, b1.y);
        o1.z = fmaf(acc[6], inv, b1.z);
        o1.w = fmaf(acc[7], inv, b1.w);
        float4* op = (float4*)&out[(size_t)r * 128 + d * 8];
        op[0] = o0;
        op[1] = o1;
    }
}

extern "C" void kernel_launch(void* const* d_in, const int* in_sizes, int n_in,
                              void* d_out, int out_size, void* d_ws, size_t ws_size,
                              hipStream_t stream)
{
    const float* H    = (const float*)d_in[0];
    const float* W    = (const float*)d_in[1];
    const float* bias = (const float*)d_in[2];
    const int*   row  = (const int*)d_in[3];
    const int*   col  = (const int*)d_in[4];
    const int N = in_sizes[0] / 128;
    const int E = in_sizes[3];

    const int nchunk = (E + CHUNK_E - 1) / CHUNK_E;   // 196
    const int nb2    = (N + RPB - 1) / RPB;           // 782

    auto align = [](size_t x) { return (x + 255) & ~(size_t)255; };

    char* ws = (char*)d_ws;
    size_t off = 0;
    unsigned short* Hpb       = (unsigned short*)(ws + off); off = align(off + (size_t)N * 128 * 2);
    unsigned short* Ht        = (unsigned short*)(ws + off); off = align(off + (size_t)nb2 * nchunk * 2);
    unsigned short* rel       = (unsigned short*)(ws + off); off = align(off + (size_t)nb2 * nchunk * 2);
    int*            totals    = (int*)(ws + off);            off = align(off + (size_t)nb2 * 4);
    int*            bucketptr = (int*)(ws + off);            off = align(off + (size_t)(nb2 + 1) * 4);
    int*            rowptr    = (int*)(ws + off);            off = align(off + (size_t)(N + 1) * 4);
    unsigned int*   WhiG      = (unsigned int*)(ws + off);   off = align(off + 8192 * 4);
    int*            colsort   = (int*)(ws + off);

    const int gemmBlocks = (N + 127) / 128;

    wsplit<<<8, 256, 0, stream>>>(W, WhiG);
    gemm_hist<<<gemmBlocks + nchunk, 512, 0, stream>>>(H, WhiG, Hpb, N,
                                                       row, Ht, E, nchunk, nb2,
                                                       gemmBlocks);
    bucket_scan<<<nb2, 256, 0, stream>>>(Ht, rel, totals, nchunk);
    bucket_ptr_scan<<<1, 1024, 0, stream>>>(totals, bucketptr, nb2);
    chunk_scatter<<<nchunk, 256, 0, stream>>>(row, col, rel, bucketptr,
                                              colsort, E, nchunk, nb2);
    bucket_sort<<<nb2, 256, 0, stream>>>(bucketptr, rowptr, colsort, N);
    aggregate_kernel<<<(N + 3) / 4, 256, 0, stream>>>(Hpb, rowptr, colsort, bias,
                                                      (float*)d_out, N);
}